// Round 1
// baseline (67.868 us; speedup 1.0000x reference)
//
#include <hip/hip_runtime.h>

#define SEQ 1024

typedef __attribute__((ext_vector_type(2))) float f2;

// h storage: row k = two 16B slots s=2k and s=2k+1; physical 16B-slot index
//   P(s) = s ^ ((s>>6)&7)   (word address = 4*P).
// Bijective (bits 0..2 XORed by untouched bits 6..8) -> no row collisions.
// Stage-2 read: 16 distinct slots/wave, clusters (s&7)^(m>>1) hit exactly
// 2x each -> 2-way, free (m136).
static __device__ __forceinline__ int slot_addr(int s) {
    return (s ^ ((s >> 6) & 7)) << 2;
}

// Closed-form qlayer for one token row y[0..7]:
// angles a = {y0+t0, y1+t1, y2+y3+t2, t3, y4+t4, y5+t5, y6+t6, y7+t7}
// c_w = cos(a_w); out[0] = c1..c7, out[w] = c0..cw (w>=1).
static __device__ __forceinline__ void qrow(const float th[8], const float y[8], float o[8]) {
    float a[8];
    a[0] = y[0] + th[0];
    a[1] = y[1] + th[1];
    a[2] = y[2] + y[3] + th[2];
    a[3] = th[3];
    a[4] = y[4] + th[4];
    a[5] = y[5] + th[5];
    a[6] = y[6] + th[6];
    a[7] = y[7] + th[7];
    float c[8];
#pragma unroll
    for (int w = 0; w < 8; ++w) c[w] = __cosf(a[w]);
    o[1] = c[0] * c[1];
#pragma unroll
    for (int w = 2; w < 8; ++w) o[w] = o[w - 1] * c[w];
    float s = c[7];
#pragma unroll
    for (int w = 6; w >= 1; --w) s *= c[w];
    o[0] = s;
}

// Fused qlayer -> 2-head attention (dk=4) -> qlayer.
// v2 (occupancy push): grid 1024 blocks (16 batches x 64 query-tiles of 16),
// 256 threads, __launch_bounds__(256,4) -> 4 blocks/CU = 16 waves/CU
// (4/SIMD, 2x the previous 2/SIMD). LDS cut to 33.4 KB/block by a shfl-xor
// pre-reduction (partials 44 KB -> 22 KB, overlaid in the 32 KB h region).
//
// Wave wv = key quarter (256 keys); lane: g = query group (4 q each),
// m = 16-key chunk. Inner loop 16 iterations (half of v1). All groups read
// the same key row -> LDS broadcast: 16 distinct 16B slots/wave ~= 2 clk.
__global__ __launch_bounds__(256, 4) void mhaq_fused(const float* __restrict__ x,
                                                     const float* __restrict__ theta,
                                                     float* __restrict__ out) {
    // phase 1: h = 1024 rows x 2 slots = 8192 words (XOR-swizzled, no pad)
    // phase 2 (overlays h after barrier): partials 128 rows x 44 words = 5632
    // res: 16 q x 10 vals
    __shared__ __align__(16) float smem[8192 + 160];
    float* const res = smem + 8192;

    const int b   = blockIdx.x >> 6;         // batch
    const int qof = (blockIdx.x & 63) << 4;  // first query of this block's 16
    const int t   = threadIdx.x;

    float th[8];
#pragma unroll
    for (int w = 0; w < 8; ++w) th[w] = theta[w];

    // ---- Stage 1: h[b] (1024 x 8) into LDS ----
    const float4* xb = (const float4*)(x + (size_t)b * SEQ * 8);
    float4 v0[4], v1[4];
#pragma unroll
    for (int r = 0; r < 4; ++r) {
        const int k = t + (r << 8);
        v0[r] = xb[2 * k];
        v1[r] = xb[2 * k + 1];
    }
#pragma unroll
    for (int r = 0; r < 4; ++r) {
        const int k = t + (r << 8);
        const float y[8] = {v0[r].x, v0[r].y, v0[r].z, v0[r].w,
                            v1[r].x, v1[r].y, v1[r].z, v1[r].w};
        float o[8];
        qrow(th, y, o);
        *(float4*)&smem[slot_addr(2 * k)]     = make_float4(o[0], o[1], o[2], o[3]);
        *(float4*)&smem[slot_addr(2 * k + 1)] = make_float4(o[4], o[5], o[6], o[7]);
    }
    __syncthreads();

    // ---- Stage 2: inner attention loop ----
    const int lane = t & 63;
    const int wv   = t >> 6;      // key quarter 0..3 (256 keys each)
    const int g    = lane >> 4;   // query group 0..3
    const int m    = lane & 15;   // key sub-chunk 0..15 (16 keys each)
    const int q0   = qof + (g << 2);  // first of this lane's 4 queries

    const float qscale = 0.5f * 1.44269504f;  // 1/sqrt(dk) * log2(e)
    f2 qv[4][4];
#pragma unroll
    for (int qq = 0; qq < 4; ++qq) {
        const float4 qa = *(const float4*)&smem[slot_addr(2 * (q0 + qq))];      // broadcast
        const float4 qb = *(const float4*)&smem[slot_addr(2 * (q0 + qq) + 1)];  // broadcast
        qv[qq][0] = f2{qa.x, qa.y} * qscale;
        qv[qq][1] = f2{qa.z, qa.w} * qscale;
        qv[qq][2] = f2{qb.x, qb.y} * qscale;
        qv[qq][3] = f2{qb.z, qb.w} * qscale;
    }

    float l0[4] = {0.f, 0.f, 0.f, 0.f};
    float l1[4] = {0.f, 0.f, 0.f, 0.f};
    f2 a01[4], a23[4], a45[4], a67[4];
#pragma unroll
    for (int qq = 0; qq < 4; ++qq) {
        a01[qq] = f2{0.f, 0.f};
        a23[qq] = f2{0.f, 0.f};
        a45[qq] = f2{0.f, 0.f};
        a67[qq] = f2{0.f, 0.f};
    }

    const int kbase = (wv << 8) + (m << 4);  // this lane's 16-key chunk
#pragma unroll 4
    for (int i = 0; i < 16; ++i) {
        const int s0 = (kbase + i) << 1;
        const float4 k0 = *(const float4*)&smem[slot_addr(s0)];
        const float4 k1 = *(const float4*)&smem[slot_addr(s0 + 1)];
        const f2 k01 = {k0.x, k0.y}, k23 = {k0.z, k0.w};
        const f2 k45 = {k1.x, k1.y}, k67 = {k1.z, k1.w};
#pragma unroll
        for (int qq = 0; qq < 4; ++qq) {
            const f2 d0 = qv[qq][0] * k01 + qv[qq][1] * k23;
            const f2 d1 = qv[qq][2] * k45 + qv[qq][3] * k67;
            const float e0 = __builtin_amdgcn_exp2f(d0.x + d0.y);
            const float e1 = __builtin_amdgcn_exp2f(d1.x + d1.y);
            l0[qq] += e0;
            l1[qq] += e1;
            const f2 e0v = {e0, e0}, e1v = {e1, e1};
            a01[qq] += e0v * k01;
            a23[qq] += e0v * k23;
            a45[qq] += e1v * k45;
            a67[qq] += e1v * k67;
        }
    }

    // ---- xor-8 pre-reduction (pairs m and m^8 within each 16-lane group) ----
    float buf[40];
#pragma unroll
    for (int qq = 0; qq < 4; ++qq) {
        buf[qq * 10 + 0] = l0[qq];
        buf[qq * 10 + 1] = l1[qq];
        buf[qq * 10 + 2] = a01[qq].x;
        buf[qq * 10 + 3] = a01[qq].y;
        buf[qq * 10 + 4] = a23[qq].x;
        buf[qq * 10 + 5] = a23[qq].y;
        buf[qq * 10 + 6] = a45[qq].x;
        buf[qq * 10 + 7] = a45[qq].y;
        buf[qq * 10 + 8] = a67[qq].x;
        buf[qq * 10 + 9] = a67[qq].y;
    }
#pragma unroll
    for (int i = 0; i < 40; ++i) buf[i] += __shfl_xor(buf[i], 8, 64);

    __syncthreads();  // all waves done reading h -> safe to overlay partials

    // ---- partial dump: only m<8 lanes, 128 rows x 44 words (22 KB) ----
    // row rid = wv*32 + g*8 + m; stride 44 words -> write clusters
    // (12*rid+4i)/4 mod 8 cycle all 8 -> 4-way = bank-time-minimal for 512B.
    if (m < 8) {
        const int rid = (wv << 5) + (g << 3) + m;
        float4* pp = (float4*)&smem[rid * 44];  // 176 B stride, 16B-aligned
#pragma unroll
        for (int i = 0; i < 10; ++i) pp[i] = ((const float4*)buf)[i];
    }
    __syncthreads();

    // ---- combine: 160 units (16 q x 10 j), each sums 32 contribs ----
    if (t < 160) {
        const int q  = t / 10;
        const int j  = t - q * 10;
        const int gg = q >> 2, qq = q & 3;
        float s = 0.f;
#pragma unroll
        for (int w = 0; w < 4; ++w)
#pragma unroll
            for (int mm = 0; mm < 8; ++mm)
                s += smem[((w << 5) + (gg << 3) + mm) * 44 + qq * 10 + j];
        res[q * 10 + j] = s;
    }
    __syncthreads();

    // ---- epilogue: thread q < 16 finalizes query qof+q ----
    if (t < 16) {
        const float* r = &res[t * 10];
        const float inv0 = 1.0f / r[0];
        const float inv1 = 1.0f / r[1];
        const float y[8] = {r[2] * inv0, r[3] * inv0, r[4] * inv0, r[5] * inv0,
                            r[6] * inv1, r[7] * inv1, r[8] * inv1, r[9] * inv1};
        float o[8];
        qrow(th, y, o);
        float4* op = (float4*)(out + ((size_t)(b * SEQ + qof + t)) * 8);
        op[0] = make_float4(o[0], o[1], o[2], o[3]);
        op[1] = make_float4(o[4], o[5], o[6], o[7]);
    }
}

extern "C" void kernel_launch(void* const* d_in, const int* in_sizes, int n_in,
                              void* d_out, int out_size, void* d_ws, size_t ws_size,
                              hipStream_t stream) {
    const float* x     = (const float*)d_in[0];
    const float* theta = (const float*)d_in[1];
    float* out         = (float*)d_out;
    mhaq_fused<<<dim3(1024), dim3(256), 0, stream>>>(x, theta, out);
}